// Round 1
// baseline (8339.360 us; speedup 1.0000x reference)
//
#include <hip/hip_runtime.h>
#include <math.h>

#define Lt 512   // timesteps
#define Bn 128   // batch
#define Dd 512   // input dim
#define Hh 512   // hidden dim

// ---------------------------------------------------------------------------
// Transpose Wh_w [j][k] -> WhT [k][j] so the recurrence reads are coalesced
// (lanes = consecutive j, h[k] is an LDS broadcast).
// ---------------------------------------------------------------------------
__global__ void transpose_kernel(const float* __restrict__ Wh,
                                 float* __restrict__ WhT) {
    __shared__ float tile[32][33];
    int bx = blockIdx.x;  // j tile
    int by = blockIdx.y;  // k tile
    int tx = threadIdx.x; // 0..31
    int ty = threadIdx.y; // 0..7
    #pragma unroll
    for (int i = 0; i < 32; i += 8) {
        tile[ty + i][tx] = Wh[(size_t)(bx * 32 + ty + i) * Hh + by * 32 + tx];
    }
    __syncthreads();
    #pragma unroll
    for (int i = 0; i < 32; i += 8) {
        WhT[(size_t)(by * 32 + ty + i) * Hh + bx * 32 + tx] = tile[tx][ty + i];
    }
}

// ---------------------------------------------------------------------------
// xproj = x @ Wx_w^T + Wx_b + Wh_b, written into the hAll region of d_out.
// C[M=L*B, N=H], A=x[M,K=D] row-major, B=Wx_w[N,K] row-major (BT GEMM).
// 64x64 tile, 256 threads, 4x4 micro-tile, fp32.
// ---------------------------------------------------------------------------
__global__ __launch_bounds__(256) void xproj_kernel(
    const float* __restrict__ A, const float* __restrict__ Bw,
    const float* __restrict__ biasx, const float* __restrict__ biash,
    float* __restrict__ C) {
    __shared__ float As[64][17];  // +1 pad: breaks ty-stride bank conflicts
    __shared__ float Bs[64][17];

    int tid = threadIdx.x;
    int nt = blockIdx.x % (Hh / 64);
    int mt = blockIdx.x / (Hh / 64);
    int rowBase = mt * 64;
    int colBase = nt * 64;
    int tx = tid % 16;  // n direction
    int ty = tid / 16;  // m direction

    int lrow = tid / 4;
    int lk4 = (tid % 4) * 4;

    float acc[4][4] = {};

    for (int k0 = 0; k0 < Dd; k0 += 16) {
        float4 av = *(const float4*)(A + (size_t)(rowBase + lrow) * Dd + k0 + lk4);
        float4 bv = *(const float4*)(Bw + (size_t)(colBase + lrow) * Dd + k0 + lk4);
        __syncthreads();
        As[lrow][lk4 + 0] = av.x; As[lrow][lk4 + 1] = av.y;
        As[lrow][lk4 + 2] = av.z; As[lrow][lk4 + 3] = av.w;
        Bs[lrow][lk4 + 0] = bv.x; Bs[lrow][lk4 + 1] = bv.y;
        Bs[lrow][lk4 + 2] = bv.z; Bs[lrow][lk4 + 3] = bv.w;
        __syncthreads();
        #pragma unroll
        for (int k = 0; k < 16; ++k) {
            float a0 = As[ty * 4 + 0][k];
            float a1 = As[ty * 4 + 1][k];
            float a2 = As[ty * 4 + 2][k];
            float a3 = As[ty * 4 + 3][k];
            float b0 = Bs[tx * 4 + 0][k];
            float b1 = Bs[tx * 4 + 1][k];
            float b2 = Bs[tx * 4 + 2][k];
            float b3 = Bs[tx * 4 + 3][k];
            acc[0][0] += a0 * b0; acc[0][1] += a0 * b1; acc[0][2] += a0 * b2; acc[0][3] += a0 * b3;
            acc[1][0] += a1 * b0; acc[1][1] += a1 * b1; acc[1][2] += a1 * b2; acc[1][3] += a1 * b3;
            acc[2][0] += a2 * b0; acc[2][1] += a2 * b1; acc[2][2] += a2 * b2; acc[2][3] += a2 * b3;
            acc[3][0] += a3 * b0; acc[3][1] += a3 * b1; acc[3][2] += a3 * b2; acc[3][3] += a3 * b3;
        }
    }

    #pragma unroll
    for (int i = 0; i < 4; ++i) {
        int row = rowBase + ty * 4 + i;
        #pragma unroll
        for (int j = 0; j < 4; ++j) {
            int col = colBase + tx * 4 + j;
            C[(size_t)row * Hh + col] = acc[i][j] + biasx[col] + biash[col];
        }
    }
}

// ---------------------------------------------------------------------------
// Recurrence: h_t = tanh(xproj_t + Wh @ h_{t-1}) per batch row.
// 64 workgroups x 256 threads; each wg owns 2 independent batch chains with
// h kept in LDS for all 512 steps (no inter-wg sync needed). WhT streamed
// from L2 (1 MB, L2-resident), amortized over 2 rows. Each thread owns
// output neurons j0=2*tid, j1=2*tid+1 for both rows.
// hAll is read (xproj) and overwritten (h_t) in place in d_out.
// ---------------------------------------------------------------------------
__global__ __launch_bounds__(256) void rnn_kernel(
    const float* __restrict__ h0in, const float* __restrict__ WhT,
    float* __restrict__ out) {
    __shared__ float hbuf[2][2][Hh];  // [buffer][local batch][k]

    int wg = blockIdx.x;  // 0..63
    int b0 = wg * 2;
    int b1 = wg * 2 + 1;
    int tid = threadIdx.x;
    int j0 = tid * 2;

    for (int k = tid; k < Hh; k += 256) {
        hbuf[0][0][k] = h0in[(size_t)b0 * Hh + k];
        hbuf[0][1][k] = h0in[(size_t)b1 * Hh + k];
    }
    __syncthreads();

    int cur = 0;
    for (int t = 0; t < Lt; ++t) {
        float acc00 = 0.f, acc01 = 0.f, acc10 = 0.f, acc11 = 0.f;
        const float* wp = WhT + j0;
        #pragma unroll 2
        for (int k4 = 0; k4 < Hh; k4 += 4) {
            float2 w0 = *(const float2*)(wp);
            float2 w1 = *(const float2*)(wp + Hh);
            float2 w2 = *(const float2*)(wp + 2 * Hh);
            float2 w3 = *(const float2*)(wp + 3 * Hh);
            float4 ha = *(const float4*)&hbuf[cur][0][k4];
            float4 hb = *(const float4*)&hbuf[cur][1][k4];
            acc00 += w0.x * ha.x; acc01 += w0.y * ha.x;
            acc10 += w0.x * hb.x; acc11 += w0.y * hb.x;
            acc00 += w1.x * ha.y; acc01 += w1.y * ha.y;
            acc10 += w1.x * hb.y; acc11 += w1.y * hb.y;
            acc00 += w2.x * ha.z; acc01 += w2.y * ha.z;
            acc10 += w2.x * hb.z; acc11 += w2.y * hb.z;
            acc00 += w3.x * ha.w; acc01 += w3.y * ha.w;
            acc10 += w3.x * hb.w; acc11 += w3.y * hb.w;
            wp += 4 * Hh;
        }

        size_t base0 = ((size_t)t * Bn + b0) * Hh + j0;
        size_t base1 = ((size_t)t * Bn + b1) * Hh + j0;
        float2 xp0 = *(const float2*)&out[base0];
        float2 xp1 = *(const float2*)&out[base1];
        float v00 = tanhf(xp0.x + acc00);
        float v01 = tanhf(xp0.y + acc01);
        float v10 = tanhf(xp1.x + acc10);
        float v11 = tanhf(xp1.y + acc11);

        int nxt = cur ^ 1;
        *(float2*)&hbuf[nxt][0][j0] = make_float2(v00, v01);
        *(float2*)&hbuf[nxt][1][j0] = make_float2(v10, v11);
        *(float2*)&out[base0] = make_float2(v00, v01);
        *(float2*)&out[base1] = make_float2(v10, v11);

        if (t == Lt - 1) {
            float* hl = out + (size_t)Lt * Bn * Hh;
            *(float2*)&hl[(size_t)b0 * Hh + j0] = make_float2(v00, v01);
            *(float2*)&hl[(size_t)b1 * Hh + j0] = make_float2(v10, v11);
        }

        __syncthreads();  // nxt writes visible before next step's reads;
                          // cur reads all done before it's overwritten at t+2
        cur = nxt;
    }
}

extern "C" void kernel_launch(void* const* d_in, const int* in_sizes, int n_in,
                              void* d_out, int out_size, void* d_ws, size_t ws_size,
                              hipStream_t stream) {
    const float* x    = (const float*)d_in[0];  // [L,B,D]
    const float* h0   = (const float*)d_in[1];  // [B,H]
    const float* Wx_w = (const float*)d_in[2];  // [H,D]
    const float* Wx_b = (const float*)d_in[3];  // [H]
    const float* Wh_w = (const float*)d_in[4];  // [H,H]
    const float* Wh_b = (const float*)d_in[5];  // [H]
    float* out = (float*)d_out;                 // hAll [L,B,H] ++ h_last [B,H]
    float* WhT = (float*)d_ws;                  // 1 MB scratch

    transpose_kernel<<<dim3(Hh / 32, Hh / 32), dim3(32, 8), 0, stream>>>(Wh_w, WhT);
    xproj_kernel<<<(Lt * Bn / 64) * (Hh / 64), 256, 0, stream>>>(x, Wx_w, Wx_b, Wh_b, out);
    rnn_kernel<<<Bn / 2, 256, 0, stream>>>(h0, WhT, out);
}

// Round 2
// 4623.628 us; speedup vs baseline: 1.8036x; 1.8036x over previous
//
#include <hip/hip_runtime.h>
#include <math.h>

#define Lt 512   // timesteps
#define Bn 128   // batch
#define Dd 512   // input dim
#define Hh 512   // hidden dim

typedef __attribute__((ext_vector_type(4))) float f32x4;
typedef __attribute__((ext_vector_type(8))) __bf16 bf16x8;
typedef __attribute__((ext_vector_type(8))) unsigned short u16x8;

__device__ __forceinline__ unsigned short f2bf(float f) {
    unsigned u = __float_as_uint(f);
    u = (u + 0x7FFFu + ((u >> 16) & 1u)) >> 16;  // RNE
    return (unsigned short)u;
}
__device__ __forceinline__ float bf2f(unsigned short s) {
    return __uint_as_float(((unsigned)s) << 16);
}

// ---------------------------------------------------------------------------
// Zero the per-step sync flags (d_ws is poisoned 0xAA before every launch).
// ---------------------------------------------------------------------------
__global__ void zero_flags_kernel(unsigned* __restrict__ flags) {
    int i = blockIdx.x * 256 + threadIdx.x;
    if (i < Lt * 8) flags[i] = 0;
}

// ---------------------------------------------------------------------------
// xproj = x @ Wx_w^T + Wx_b + Wh_b  (fp32, unchanged from round 1)
// ---------------------------------------------------------------------------
__global__ __launch_bounds__(256) void xproj_kernel(
    const float* __restrict__ A, const float* __restrict__ Bw,
    const float* __restrict__ biasx, const float* __restrict__ biash,
    float* __restrict__ C) {
    __shared__ float As[64][17];
    __shared__ float Bs[64][17];

    int tid = threadIdx.x;
    int nt = blockIdx.x % (Hh / 64);
    int mt = blockIdx.x / (Hh / 64);
    int rowBase = mt * 64;
    int colBase = nt * 64;
    int tx = tid % 16;
    int ty = tid / 16;
    int lrow = tid / 4;
    int lk4 = (tid % 4) * 4;

    float acc[4][4] = {};

    for (int k0 = 0; k0 < Dd; k0 += 16) {
        float4 av = *(const float4*)(A + (size_t)(rowBase + lrow) * Dd + k0 + lk4);
        float4 bv = *(const float4*)(Bw + (size_t)(colBase + lrow) * Dd + k0 + lk4);
        __syncthreads();
        As[lrow][lk4 + 0] = av.x; As[lrow][lk4 + 1] = av.y;
        As[lrow][lk4 + 2] = av.z; As[lrow][lk4 + 3] = av.w;
        Bs[lrow][lk4 + 0] = bv.x; Bs[lrow][lk4 + 1] = bv.y;
        Bs[lrow][lk4 + 2] = bv.z; Bs[lrow][lk4 + 3] = bv.w;
        __syncthreads();
        #pragma unroll
        for (int k = 0; k < 16; ++k) {
            float a0 = As[ty * 4 + 0][k];
            float a1 = As[ty * 4 + 1][k];
            float a2 = As[ty * 4 + 2][k];
            float a3 = As[ty * 4 + 3][k];
            float b0 = Bs[tx * 4 + 0][k];
            float b1 = Bs[tx * 4 + 1][k];
            float b2 = Bs[tx * 4 + 2][k];
            float b3 = Bs[tx * 4 + 3][k];
            acc[0][0] += a0 * b0; acc[0][1] += a0 * b1; acc[0][2] += a0 * b2; acc[0][3] += a0 * b3;
            acc[1][0] += a1 * b0; acc[1][1] += a1 * b1; acc[1][2] += a1 * b2; acc[1][3] += a1 * b3;
            acc[2][0] += a2 * b0; acc[2][1] += a2 * b1; acc[2][2] += a2 * b2; acc[2][3] += a2 * b3;
            acc[3][0] += a3 * b0; acc[3][1] += a3 * b1; acc[3][2] += a3 * b2; acc[3][3] += a3 * b3;
        }
    }

    #pragma unroll
    for (int i = 0; i < 4; ++i) {
        int row = rowBase + ty * 4 + i;
        #pragma unroll
        for (int j = 0; j < 4; ++j) {
            int col = colBase + tx * 4 + j;
            C[(size_t)row * Hh + col] = acc[i][j] + biasx[col] + biash[col];
        }
    }
}

// ---------------------------------------------------------------------------
// Recurrence, j-split across 256 wgs with flag sync.
//   grid: 8 batch-groups (16 b each) x 32 j-groups (16 j each) = 256 wgs.
//   Wh slice (16 j-rows) resident in LDS as bf16 hi/lo for the whole run.
//   Per step: z[16b][16j] = sum_k h[b][k]*Wh[j][k] via mfma_f32_16x16x32_bf16,
//   3 products (Ah*Bh + Ah*Bl + Al*Bh) for ~fp32 accuracy. Waves split k.
//   h passed between steps via double-buffered packed bf16-hi/lo u32 array in
//   d_ws; per-(bg,t) flag counters (fan-in 32) with agent-scope release/acquire.
//   Deadlock-free: 256 small wgs are always co-resident on 256 CUs.
// ---------------------------------------------------------------------------
__global__ __launch_bounds__(256) void rnn_mfma_kernel(
    const float* __restrict__ h0in, const float* __restrict__ Wh,
    float* __restrict__ out, unsigned* __restrict__ hpk,
    unsigned* __restrict__ flags) {

    __shared__ unsigned short Whi[16 * 520];  // [j_local][k], +8 pad breaks banks
    __shared__ unsigned short Wlo[16 * 520];
    __shared__ float psum[4 * 64 * 4];        // [wave][lane][reg]

    const int tid = threadIdx.x;
    const int bg = blockIdx.x & 7;    // batch group: b = bg*16 ..
    const int jg = blockIdx.x >> 3;   // j group: j = jg*16 ..
    const int b0g = bg * 16;
    const int j0g = jg * 16;

    // ---- one-time: stage Wh rows j0g..j0g+15 into LDS as bf16 hi/lo ----
    #pragma unroll
    for (int it = 0; it < 8; ++it) {
        int idx = (it * 256 + tid) * 4;   // into 16x512 elements
        int j = idx >> 9;
        int k = idx & 511;
        float4 w = *(const float4*)(Wh + (size_t)(j0g + j) * Hh + k);
        int base = j * 520 + k;
        unsigned short s0 = f2bf(w.x); Whi[base + 0] = s0; Wlo[base + 0] = f2bf(w.x - bf2f(s0));
        unsigned short s1 = f2bf(w.y); Whi[base + 1] = s1; Wlo[base + 1] = f2bf(w.y - bf2f(s1));
        unsigned short s2 = f2bf(w.z); Whi[base + 2] = s2; Wlo[base + 2] = f2bf(w.z - bf2f(s2));
        unsigned short s3 = f2bf(w.w); Whi[base + 3] = s3; Wlo[base + 3] = f2bf(w.w - bf2f(s3));
    }
    __syncthreads();

    const int lane = tid & 63;
    const int wv = tid >> 6;        // wave id = k quarter
    const int rw = lane & 15;       // A: b row / B: j col
    const int quad = lane >> 4;

    const int bl_ = tid >> 4;       // epilogue: local batch
    const int jl = tid & 15;        // epilogue: local j

    for (int t = 0; t < Lt; ++t) {
        if (t > 0) {
            if (tid == 0) {
                while (__hip_atomic_load(&flags[(t - 1) * 8 + bg],
                                         __ATOMIC_ACQUIRE,
                                         __HIP_MEMORY_SCOPE_AGENT) < 32u) {
                    __builtin_amdgcn_s_sleep(2);
                }
            }
            __syncthreads();  // everyone waits for t0's acquire
        }

        f32x4 acc0 = {0.f, 0.f, 0.f, 0.f};
        f32x4 acc1 = {0.f, 0.f, 0.f, 0.f};
        const unsigned* hprev = hpk + (size_t)((t + 1) & 1) * (Bn * Hh);

        #pragma unroll
        for (int c = 0; c < 4; ++c) {
            int kk = wv * 128 + c * 32 + quad * 8;
            u16x8 ahi, alo;
            if (t == 0) {
                const float* hp = h0in + (size_t)(b0g + rw) * Hh + kk;
                float4 v0 = *(const float4*)hp;
                float4 v1 = *(const float4*)(hp + 4);
                float vv[8] = {v0.x, v0.y, v0.z, v0.w, v1.x, v1.y, v1.z, v1.w};
                #pragma unroll
                for (int i = 0; i < 8; ++i) {
                    unsigned short s = f2bf(vv[i]);
                    ahi[i] = s;
                    alo[i] = f2bf(vv[i] - bf2f(s));
                }
            } else {
                const uint4* hp = (const uint4*)(hprev + (size_t)(b0g + rw) * Hh + kk);
                uint4 p0 = hp[0];
                uint4 p1 = hp[1];
                unsigned pv[8] = {p0.x, p0.y, p0.z, p0.w, p1.x, p1.y, p1.z, p1.w};
                #pragma unroll
                for (int i = 0; i < 8; ++i) {
                    ahi[i] = (unsigned short)(pv[i] >> 16);
                    alo[i] = (unsigned short)(pv[i] & 0xFFFFu);
                }
            }
            bf16x8 aH = __builtin_bit_cast(bf16x8, ahi);
            bf16x8 aL = __builtin_bit_cast(bf16x8, alo);
            bf16x8 bH = __builtin_bit_cast(bf16x8, *(const u16x8*)(Whi + rw * 520 + kk));
            bf16x8 bL = __builtin_bit_cast(bf16x8, *(const u16x8*)(Wlo + rw * 520 + kk));
            if (c & 1) {
                acc1 = __builtin_amdgcn_mfma_f32_16x16x32_bf16(aH, bH, acc1, 0, 0, 0);
                acc1 = __builtin_amdgcn_mfma_f32_16x16x32_bf16(aH, bL, acc1, 0, 0, 0);
                acc1 = __builtin_amdgcn_mfma_f32_16x16x32_bf16(aL, bH, acc1, 0, 0, 0);
            } else {
                acc0 = __builtin_amdgcn_mfma_f32_16x16x32_bf16(aH, bH, acc0, 0, 0, 0);
                acc0 = __builtin_amdgcn_mfma_f32_16x16x32_bf16(aH, bL, acc0, 0, 0, 0);
                acc0 = __builtin_amdgcn_mfma_f32_16x16x32_bf16(aL, bH, acc0, 0, 0, 0);
            }
        }
        f32x4 accs = acc0 + acc1;
        *(f32x4*)(psum + (wv * 64 + lane) * 4) = accs;
        __syncthreads();

        // ---- epilogue: one (b,j) per thread ----
        // C/D layout: col = lane&15 (j), row = quad*4 + reg (b)
        float z = psum[((0 * 64 + (bl_ >> 2) * 16 + jl) * 4) + (bl_ & 3)]
                + psum[((1 * 64 + (bl_ >> 2) * 16 + jl) * 4) + (bl_ & 3)]
                + psum[((2 * 64 + (bl_ >> 2) * 16 + jl) * 4) + (bl_ & 3)]
                + psum[((3 * 64 + (bl_ >> 2) * 16 + jl) * 4) + (bl_ & 3)];
        size_t obase = ((size_t)t * Bn + (b0g + bl_)) * Hh + (j0g + jl);
        z += out[obase];                 // xproj (+ biases)
        float hv = tanhf(z);
        out[obase] = hv;
        if (t == Lt - 1) {
            out[(size_t)Lt * Bn * Hh + (size_t)(b0g + bl_) * Hh + (j0g + jl)] = hv;
        }
        unsigned short hi_ = f2bf(hv);
        unsigned short lo_ = f2bf(hv - bf2f(hi_));
        unsigned pk = ((unsigned)hi_ << 16) | (unsigned)lo_;
        __hip_atomic_store(hpk + (size_t)(t & 1) * (Bn * Hh)
                               + (size_t)(b0g + bl_) * Hh + (j0g + jl),
                           pk, __ATOMIC_RELAXED, __HIP_MEMORY_SCOPE_AGENT);
        __syncthreads();  // psum reads done; all stores issued & drained
        if (tid == 0) {
            __hip_atomic_fetch_add(&flags[t * 8 + bg], 1u,
                                   __ATOMIC_RELEASE, __HIP_MEMORY_SCOPE_AGENT);
        }
    }
}

extern "C" void kernel_launch(void* const* d_in, const int* in_sizes, int n_in,
                              void* d_out, int out_size, void* d_ws, size_t ws_size,
                              hipStream_t stream) {
    const float* x    = (const float*)d_in[0];  // [L,B,D]
    const float* h0   = (const float*)d_in[1];  // [B,H]
    const float* Wx_w = (const float*)d_in[2];  // [H,D]
    const float* Wx_b = (const float*)d_in[3];  // [H]
    const float* Wh_w = (const float*)d_in[4];  // [H,H]
    const float* Wh_b = (const float*)d_in[5];  // [H]
    float* out = (float*)d_out;                 // hAll [L,B,H] ++ h_last [B,H]

    unsigned* ws = (unsigned*)d_ws;
    unsigned* hpk   = ws;                       // 2 x [B][H] packed bf16 hi/lo (512 KB)
    unsigned* flags = ws + 2 * Bn * Hh;         // [Lt][8] counters (16 KB)

    zero_flags_kernel<<<(Lt * 8 + 255) / 256, 256, 0, stream>>>(flags);
    xproj_kernel<<<(Lt * Bn / 64) * (Hh / 64), 256, 0, stream>>>(x, Wx_w, Wx_b, Wh_b, out);
    rnn_mfma_kernel<<<256, 256, 0, stream>>>(h0, Wh_w, out, hpk, flags);
}